// Round 1
// baseline (211.104 us; speedup 1.0000x reference)
//
#include <hip/hip_runtime.h>

// Problem constants (B=2, L=16, D=4, K=2, N_IN=8, N_OUT=8, NC=3)
#define LSZ    16
#define NSITES (2 * LSZ * LSZ * LSZ * LSZ)   // 131072 sites
// W:     site-stride 72  floats  (8 ch * 3*3)
// U_PT:  site-stride 180 floats  (4 mu * 5 k * 3*3)
// omega: [i][j][mu][ik], i-stride 160, j-stride 20, mu-stride 5
// out:   site-stride 72  floats  (8 ch * 3*3)

__global__ __launch_bounds__(256) void lconv_kernel(
    const float* __restrict__ W, const float* __restrict__ U_PT,
    const float* __restrict__ omega, float* __restrict__ out)
{
    const int s = blockIdx.x * blockDim.x + threadIdx.x;   // site index

    float acc[8][9];
#pragma unroll
    for (int i = 0; i < 8; ++i)
#pragma unroll
        for (int e = 0; e < 9; ++e) acc[i][e] = 0.0f;

    const float* __restrict__ Ub = U_PT + (size_t)s * 180;

    for (int ik = 0; ik < 5; ++ik) {              // k = ik - 2
        const int k = ik - 2;
#pragma unroll
        for (int mu = 0; mu < 4; ++mu) {
            // --- load U (3x3) for this (mu, ik): 9 contiguous floats ---
            float U[9];
#pragma unroll
            for (int e = 0; e < 9; ++e) U[e] = Ub[(mu * 5 + ik) * 9 + e];

            // --- neighbor site: x_mu -> (x_mu + k) mod 16 ---
            const int sh = 12 - 4 * mu;           // mu=0 is axis 1 (bits 12..15)
            const int x  = (s >> sh) & 15;
            const int ns = s + ((((x + k + 16) & 15) - x) << sh);

            // --- load full 72-float W block of neighbor site (float4, 16B aligned) ---
            const float4* __restrict__ Wn4 =
                reinterpret_cast<const float4*>(W + (size_t)ns * 72);
            float Wl[72];
#pragma unroll
            for (int q = 0; q < 18; ++q) {
                const float4 v = Wn4[q];
                Wl[q * 4 + 0] = v.x; Wl[q * 4 + 1] = v.y;
                Wl[q * 4 + 2] = v.z; Wl[q * 4 + 3] = v.w;
            }

#pragma unroll
            for (int j = 0; j < 8; ++j) {
                // UW = U * W_j   (3x3 * 3x3)
                float UW[9];
#pragma unroll
                for (int a = 0; a < 3; ++a)
#pragma unroll
                    for (int d = 0; d < 3; ++d)
                        UW[a * 3 + d] =
                            fmaf(U[a * 3 + 0], Wl[j * 9 + 0 * 3 + d],
                            fmaf(U[a * 3 + 1], Wl[j * 9 + 1 * 3 + d],
                                 U[a * 3 + 2] * Wl[j * 9 + 2 * 3 + d]));
                // M = UW * U^T
                float M[9];
#pragma unroll
                for (int a = 0; a < 3; ++a)
#pragma unroll
                    for (int b2 = 0; b2 < 3; ++b2)
                        M[a * 3 + b2] =
                            fmaf(UW[a * 3 + 0], U[b2 * 3 + 0],
                            fmaf(UW[a * 3 + 1], U[b2 * 3 + 1],
                                 UW[a * 3 + 2] * U[b2 * 3 + 2]));
                // out_i += omega[i,j,mu,ik] * M   (omega loads are wave-uniform)
                const float* __restrict__ om = omega + (size_t)(j * 4 + mu) * 5 + ik;
#pragma unroll
                for (int i = 0; i < 8; ++i) {
                    const float w = om[(size_t)i * 160];
#pragma unroll
                    for (int e = 0; e < 9; ++e)
                        acc[i][e] = fmaf(w, M[e], acc[i][e]);
                }
            }
        }
    }

    float* __restrict__ o = out + (size_t)s * 72;
#pragma unroll
    for (int i = 0; i < 8; ++i)
#pragma unroll
        for (int e = 0; e < 9; ++e) o[i * 9 + e] = acc[i][e];
}

extern "C" void kernel_launch(void* const* d_in, const int* in_sizes, int n_in,
                              void* d_out, int out_size, void* d_ws, size_t ws_size,
                              hipStream_t stream) {
    const float* W   = (const float*)d_in[0];
    const float* U   = (const float*)d_in[1];
    const float* om  = (const float*)d_in[2];
    float*       out = (float*)d_out;

    const int block = 256;
    const int grid  = NSITES / block;   // 131072 / 256 = 512 blocks
    hipLaunchKernelGGL(lconv_kernel, dim3(grid), dim3(block), 0, stream,
                       W, U, om, out);
}

// Round 2
// 143.256 us; speedup vs baseline: 1.4736x; 1.4736x over previous
//
#include <hip/hip_runtime.h>

// Problem constants (B=2, L=16, D=4, K=2, N_IN=8, N_OUT=8, NC=3)
#define NSITES (2 * 16 * 16 * 16 * 16)          // 131072 sites
// W:     site-stride 72  floats (8 ch * 3*3), site base 288 B (16B aligned)
// U_PT:  site-stride 180 floats (4 mu * 5 ik * 3*3)
// omega: flat [i][j][mu][ik] = i*160 + j*20 + mu*5 + ik  (1280 floats)
// out:   site-stride 72 floats

__global__ __launch_bounds__(256) void lconv_kernel(
    const float* __restrict__ W, const float* __restrict__ U_PT,
    const float* __restrict__ omega, float* __restrict__ out)
{
    __shared__ float s_om[1280];
    for (int t = threadIdx.x; t < 1280; t += 256) s_om[t] = omega[t];
    __syncthreads();

    // XCD-aware bijective swizzle: 2048 blocks, 8 XCDs, 256-block chunks.
    const int bid  = ((int)blockIdx.x & 7) * ((int)gridDim.x >> 3)
                   + ((int)blockIdx.x >> 3);
    const int idx  = bid * 256 + (int)threadIdx.x;
    const int s    = idx >> 2;        // site
    const int mu   = idx & 3;         // this thread's axis
    const int sh   = 12 - 4 * mu;     // bit position of x_mu in s
    const int x    = (s >> sh) & 15;

    const float* __restrict__ Ub = U_PT + (size_t)s * 180 + (size_t)mu * 45;

    float acc[8][9];
#pragma unroll
    for (int i = 0; i < 8; ++i)
#pragma unroll
        for (int e = 0; e < 9; ++e) acc[i][e] = 0.0f;

    for (int ik = 0; ik < 5; ++ik) {
        const int k = ik - 2;
        // U (3x3) for (mu, ik): 9 contiguous floats (4B aligned)
        float U[9];
#pragma unroll
        for (int e = 0; e < 9; ++e) U[e] = Ub[ik * 9 + e];

        // neighbor site along mu: x_mu -> (x_mu + k) mod 16
        const int ns = s + ((((x + k + 16) & 15) - x) << sh);
        const float4* __restrict__ Wn4 =
            reinterpret_cast<const float4*>(W + (size_t)ns * 72);

        // process j in two halves of 4 to bound VGPR pressure
#pragma unroll
        for (int jh = 0; jh < 2; ++jh) {
            float Wl[36];
#pragma unroll
            for (int q = 0; q < 9; ++q) {
                const float4 v = Wn4[jh * 9 + q];
                Wl[q * 4 + 0] = v.x; Wl[q * 4 + 1] = v.y;
                Wl[q * 4 + 2] = v.z; Wl[q * 4 + 3] = v.w;
            }
#pragma unroll
            for (int jj = 0; jj < 4; ++jj) {
                const int j = jh * 4 + jj;
                // UW = U * W_j
                float UW[9];
#pragma unroll
                for (int a = 0; a < 3; ++a)
#pragma unroll
                    for (int d = 0; d < 3; ++d)
                        UW[a * 3 + d] =
                            fmaf(U[a * 3 + 0], Wl[jj * 9 + 0 * 3 + d],
                            fmaf(U[a * 3 + 1], Wl[jj * 9 + 1 * 3 + d],
                                 U[a * 3 + 2] * Wl[jj * 9 + 2 * 3 + d]));
                // M = UW * U^T
                float M[9];
#pragma unroll
                for (int a = 0; a < 3; ++a)
#pragma unroll
                    for (int b2 = 0; b2 < 3; ++b2)
                        M[a * 3 + b2] =
                            fmaf(UW[a * 3 + 0], U[b2 * 3 + 0],
                            fmaf(UW[a * 3 + 1], U[b2 * 3 + 1],
                                 UW[a * 3 + 2] * U[b2 * 3 + 2]));
                // out_i += omega[i,j,mu,ik] * M   (LDS, immediate offsets)
#pragma unroll
                for (int i = 0; i < 8; ++i) {
                    const float w = s_om[i * 160 + j * 20 + mu * 5 + ik];
#pragma unroll
                    for (int e = 0; e < 9; ++e)
                        acc[i][e] = fmaf(w, M[e], acc[i][e]);
                }
            }
        }
    }

    // reduce the 4 mu-partials within each lane group of 4
#pragma unroll
    for (int i = 0; i < 8; ++i)
#pragma unroll
        for (int e = 0; e < 9; ++e) {
            float v = acc[i][e];
            v += __shfl_xor(v, 1);
            v += __shfl_xor(v, 2);
            acc[i][e] = v;
        }

    // lane mu==0 of each group writes the full 72-float site block
    if (mu == 0) {
        float4* __restrict__ o4 = reinterpret_cast<float4*>(out + (size_t)s * 72);
#pragma unroll
        for (int q = 0; q < 18; ++q) {
            const int f = q * 4;
            o4[q] = make_float4(acc[(f + 0) / 9][(f + 0) % 9],
                                acc[(f + 1) / 9][(f + 1) % 9],
                                acc[(f + 2) / 9][(f + 2) % 9],
                                acc[(f + 3) / 9][(f + 3) % 9]);
        }
    }
}

extern "C" void kernel_launch(void* const* d_in, const int* in_sizes, int n_in,
                              void* d_out, int out_size, void* d_ws, size_t ws_size,
                              hipStream_t stream) {
    const float* W   = (const float*)d_in[0];
    const float* U   = (const float*)d_in[1];
    const float* om  = (const float*)d_in[2];
    float*       out = (float*)d_out;

    const int block = 256;
    const int grid  = (NSITES * 4) / block;   // 2048 blocks
    hipLaunchKernelGGL(lconv_kernel, dim3(grid), dim3(block), 0, stream,
                       W, U, om, out);
}